// Round 1
// baseline (142.688 us; speedup 1.0000x reference)
//
#include <hip/hip_runtime.h>
#include <math.h>

#define DEV __device__ __forceinline__

DEV float dot4(float4 a, float4 b){ return a.x*b.x + a.y*b.y + a.z*b.z + a.w*b.w; }

DEV float wave_sum(float v){
  #pragma unroll
  for (int off = 32; off; off >>= 1) v += __shfl_xor(v, off, 64);
  return v;
}

DEV float gelu_exact(float v){ return 0.5f * v * (1.f + erff(v * 0.70710678118654752f)); }

// K0: transpose landmarks into float4-interleaved layout lmT4[hg][k] (hg = h/4), plus |lm_k|^2
__global__ void k_lmT(const float* __restrict__ lm, float* __restrict__ lmT4,
                      float* __restrict__ lnorm){
  int k = blockIdx.x, t = threadIdx.x;
  __shared__ float red[256];
  float s = 0.f;
  if (t < 192){
    float4 v = *(const float4*)(lm + k*768 + 4*t);
    ((float4*)lmT4)[t*64 + k] = v;
    s = dot4(v, v);
  }
  red[t] = s; __syncthreads();
  for (int off = 128; off; off >>= 1){ if (t < off) red[t] += red[t+off]; __syncthreads(); }
  if (t == 0) lnorm[k] = red[0];
}

// K1: per (b,n) row: dist to 64 landmarks (lane=k), min-max norm, gaussian sim, row-normalize.
// 4 waves/block, 2 rows/wave -> 8 rows/block, 256 blocks for 2048 rows.
__global__ void k_prob(const float* __restrict__ enc, const float* __restrict__ lmT4,
                       const float* __restrict__ lnorm, float* __restrict__ prob){
  int t = threadIdx.x, lane = t & 63, wv = t >> 6;
  int row0 = blockIdx.x*8 + wv*2;
  const float4* LT = (const float4*)lmT4;
  const float4* X0 = (const float4*)(enc + (size_t)row0*768);
  const float4* X1 = (const float4*)(enc + (size_t)(row0+1)*768);
  float dot0=0.f, dot1=0.f, xn0=0.f, xn1=0.f;
  #pragma unroll 4
  for (int hg = 0; hg < 192; ++hg){
    float4 l4 = LT[hg*64 + lane];        // coalesced across lanes
    float4 a = X0[hg], b = X1[hg];       // broadcast (uniform per wave)
    dot0 += dot4(a, l4); dot1 += dot4(b, l4);
    xn0  += dot4(a, a);  xn1  += dot4(b, b);
  }
  float ln = lnorm[lane];
  float d0 = sqrtf(fmaxf(xn0 + ln - 2.f*dot0, 0.f));
  float d1 = sqrtf(fmaxf(xn1 + ln - 2.f*dot1, 0.f));
  float mn0=d0, mx0=d0, mn1=d1, mx1=d1;
  #pragma unroll
  for (int off = 32; off; off >>= 1){
    mn0 = fminf(mn0, __shfl_xor(mn0, off, 64));
    mx0 = fmaxf(mx0, __shfl_xor(mx0, off, 64));
    mn1 = fminf(mn1, __shfl_xor(mn1, off, 64));
    mx1 = fmaxf(mx1, __shfl_xor(mx1, off, 64));
  }
  float nd0 = (d0 - mn0) / (mx0 - mn0 + 1e-6f);
  float nd1 = (d1 - mn1) / (mx1 - mn1 + 1e-6f);
  float s0 = expf(nd0*nd0 * (-1.f/0.18f));   // 2*d^2 = 2*0.3^2 = 0.18
  float s1 = expf(nd1*nd1 * (-1.f/0.18f));
  float sum0 = wave_sum(s0), sum1 = wave_sum(s1);
  prob[(size_t)row0*64 + lane]     = s0 / sum0;
  prob[(size_t)(row0+1)*64 + lane] = s1 / sum1;
}

// K2: out[b,k,h] = sum_n prob[b,n,k]*enc[b,n,h]; also mbar[b,h] = mean_k out[b,k,h].
// grid = 8 b * 24 h-chunks (32 h each); wave wv owns 8 h's for all 64 k (lane=k).
__global__ void k_pool(const float* __restrict__ enc, const float* __restrict__ prob,
                       float* __restrict__ outp, float* __restrict__ mbar){
  int b = blockIdx.x / 24, ch = blockIdx.x % 24;
  int lane = threadIdx.x & 63, wv = threadIdx.x >> 6;
  int h0 = ch*32 + wv*8;
  const float* E = enc + (size_t)b*256*768 + h0;
  const float* P = prob + (size_t)b*256*64;
  float acc[8] = {0,0,0,0,0,0,0,0};
  for (int n = 0; n < 256; ++n){
    float p = P[n*64 + lane];                              // coalesced
    float4 e0 = *(const float4*)(E + (size_t)n*768);       // broadcast
    float4 e1 = *(const float4*)(E + (size_t)n*768 + 4);
    acc[0] += p*e0.x; acc[1] += p*e0.y; acc[2] += p*e0.z; acc[3] += p*e0.w;
    acc[4] += p*e1.x; acc[5] += p*e1.y; acc[6] += p*e1.z; acc[7] += p*e1.w;
  }
  float* O = outp + ((size_t)b*64 + lane)*768 + h0;
  *(float4*)O       = make_float4(acc[0],acc[1],acc[2],acc[3]);
  *(float4*)(O + 4) = make_float4(acc[4],acc[5],acc[6],acc[7]);
  #pragma unroll
  for (int j = 0; j < 8; ++j){
    float v = wave_sum(acc[j]);
    if (lane == 0) mbar[(size_t)b*768 + h0 + j] = v * (1.f/64.f);
  }
}

// K3/4/5: o[b,j] = bias[j] + sum_i in[b,i]*W[j,i]; in is [8][768], one wave per j.
__global__ void k_vm768(const float* __restrict__ in, const float* __restrict__ W,
                        const float* __restrict__ bias, float* __restrict__ out){
  int lane = threadIdx.x & 63, wv = threadIdx.x >> 6;
  int j = blockIdx.x*4 + wv;
  const float4* Wr = (const float4*)(W + (size_t)j*768);
  const float4* IN = (const float4*)in;
  float acc[8] = {0,0,0,0,0,0,0,0};
  #pragma unroll
  for (int s = 0; s < 3; ++s){
    int ig = s*64 + lane;
    float4 w4 = Wr[ig];
    #pragma unroll
    for (int b = 0; b < 8; ++b) acc[b] += dot4(w4, IN[b*192 + ig]);
  }
  #pragma unroll
  for (int b = 0; b < 8; ++b){
    float v = wave_sum(acc[b]);
    if (lane == 0) out[b*768 + j] = v + bias[j];
  }
}

// K6pre: x[b, k*768+h] = 2*out[b,k,h] + hx3[b,h]  (outp layout already matches x)
__global__ void k_xcat(const float* __restrict__ outp, const float* __restrict__ hx3,
                       float* __restrict__ x){
  int idx = blockIdx.x*256 + threadIdx.x;      // float4 index, 98304 total
  int h4 = idx % 192;
  int b  = idx / (192*64);
  float4 o = ((const float4*)outp)[idx];
  float4 g = ((const float4*)hx3)[b*192 + h4];
  float4 r;
  r.x = 2.f*o.x + g.x; r.y = 2.f*o.y + g.y; r.z = 2.f*o.z + g.z; r.w = 2.f*o.w + g.w;
  ((float4*)x)[idx] = r;
}

// K6: fc1 raw sums. Block = 4 waves, owns 4 j-rows; each wave covers a K-quarter for all 8 b.
// Streams 196.6 MB of fc1_w once (the HBM floor); x is L2-resident.
__global__ void k_fc1(const float* __restrict__ x, const float* __restrict__ W,
                      float* __restrict__ y1raw){
  int lane = threadIdx.x & 63, wv = threadIdx.x >> 6;
  int j0 = blockIdx.x*4;
  const float4* X  = (const float4*)x;
  const float4* W0 = (const float4*)(W + (size_t)(j0+0)*49152);
  const float4* W1 = (const float4*)(W + (size_t)(j0+1)*49152);
  const float4* W2 = (const float4*)(W + (size_t)(j0+2)*49152);
  const float4* W3 = (const float4*)(W + (size_t)(j0+3)*49152);
  float acc[4][8];
  #pragma unroll
  for (int jj = 0; jj < 4; ++jj)
    #pragma unroll
    for (int b = 0; b < 8; ++b) acc[jj][b] = 0.f;
  int base = wv*3072;
  for (int s = 0; s < 48; ++s){
    int ig = base + s*64 + lane;
    float4 w0 = W0[ig], w1 = W1[ig], w2 = W2[ig], w3 = W3[ig];
    #pragma unroll
    for (int b = 0; b < 8; ++b){
      float4 xv = X[b*12288 + ig];
      acc[0][b] += dot4(w0, xv); acc[1][b] += dot4(w1, xv);
      acc[2][b] += dot4(w2, xv); acc[3][b] += dot4(w3, xv);
    }
  }
  __shared__ float part[4][32];
  #pragma unroll
  for (int jj = 0; jj < 4; ++jj)
    #pragma unroll
    for (int b = 0; b < 8; ++b){
      float v = wave_sum(acc[jj][b]);
      if (lane == 0) part[wv][jj*8 + b] = v;
    }
  __syncthreads();
  if (threadIdx.x < 32){
    int jj = threadIdx.x >> 3, b = threadIdx.x & 7;
    float v = part[0][threadIdx.x] + part[1][threadIdx.x]
            + part[2][threadIdx.x] + part[3][threadIdx.x];
    y1raw[b*1000 + j0 + jj] = v;
  }
}

// K7: x1 = gelu(y1raw + fc1_b)
__global__ void k_gelu1(const float* __restrict__ y, const float* __restrict__ bias,
                        float* __restrict__ x1){
  int idx = blockIdx.x*256 + threadIdx.x;
  if (idx < 8000){
    int j = idx % 1000;
    x1[idx] = gelu_exact(y[idx] + bias[j]);
  }
}

// K8: x2[b,m] = gelu(sum_j x1[b,j]*fc2_w[m,j] + fc2_b[m]); one wave per m.
__global__ void k_fc2(const float* __restrict__ x1, const float* __restrict__ W,
                      const float* __restrict__ bias, float* __restrict__ x2){
  int lane = threadIdx.x & 63, wv = threadIdx.x >> 6;
  int m = blockIdx.x*4 + wv;
  const float4* Wr = (const float4*)(W + (size_t)m*1000);
  const float4* X  = (const float4*)x1;
  float acc[8] = {0,0,0,0,0,0,0,0};
  for (int s = 0; s < 4; ++s){
    int jg = s*64 + lane;
    if (jg < 250){
      float4 w4 = Wr[jg];
      #pragma unroll
      for (int b = 0; b < 8; ++b) acc[b] += dot4(w4, X[b*250 + jg]);
    }
  }
  #pragma unroll
  for (int b = 0; b < 8; ++b){
    float v = wave_sum(acc[b]);
    if (lane == 0) x2[b*100 + m] = gelu_exact(v + bias[m]);
  }
}

// K9: out[b,c] = x2[b,:] . fc3_w[c,:] + fc3_b[c]
__global__ void k_fc3(const float* __restrict__ x2, const float* __restrict__ W,
                      const float* __restrict__ bias, float* __restrict__ out){
  int t = threadIdx.x;
  if (t < 80){
    int b = t/10, c = t%10;
    float acc = bias[c];
    for (int m = 0; m < 100; ++m) acc += x2[b*100+m] * W[c*100+m];
    out[t] = acc;
  }
}

extern "C" void kernel_launch(void* const* d_in, const int* in_sizes, int n_in,
                              void* d_out, int out_size, void* d_ws, size_t ws_size,
                              hipStream_t stream){
  const float* enc = (const float*)d_in[0];
  const float* lm  = (const float*)d_in[1];
  // d_in[2] = alpha: provably unused — G = P dw P^T is strictly positive for any
  // alpha (dw diagonal = 1), so A=(G!=0) is all-ones and An = J/64.
  const float* w1  = (const float*)d_in[3];
  const float* b1  = (const float*)d_in[4];
  const float* w2  = (const float*)d_in[5];
  const float* b2  = (const float*)d_in[6];
  const float* w3  = (const float*)d_in[7];
  const float* b3  = (const float*)d_in[8];
  const float* fw1 = (const float*)d_in[9];
  const float* fb1 = (const float*)d_in[10];
  const float* fw2 = (const float*)d_in[11];
  const float* fb2 = (const float*)d_in[12];
  const float* fw3 = (const float*)d_in[13];
  const float* fb3 = (const float*)d_in[14];

  float* ws    = (float*)d_ws;
  float* lmT4  = ws;               // 49152
  float* lnorm = lmT4  + 49152;    // 64
  float* prob  = lnorm + 64;       // 131072
  float* outp  = prob  + 131072;   // 393216
  float* mbar  = outp  + 393216;   // 6144
  float* hx1   = mbar  + 6144;     // 6144
  float* hx2   = hx1   + 6144;     // 6144
  float* hx3   = hx2   + 6144;     // 6144
  float* xcat  = hx3   + 6144;     // 393216
  float* y1raw = xcat  + 393216;   // 8000
  float* x1    = y1raw + 8000;     // 8000
  float* x2    = x1    + 8000;     // 800
  float* out   = (float*)d_out;

  k_lmT  <<<64, 256, 0, stream>>>(lm, lmT4, lnorm);
  k_prob <<<256,256, 0, stream>>>(enc, lmT4, lnorm, prob);
  k_pool <<<192,256, 0, stream>>>(enc, prob, outp, mbar);
  k_vm768<<<192,256, 0, stream>>>(mbar, w1, b1, hx1);
  k_vm768<<<192,256, 0, stream>>>(hx1,  w2, b2, hx2);
  k_vm768<<<192,256, 0, stream>>>(hx2,  w3, b3, hx3);
  k_xcat <<<384,256, 0, stream>>>(outp, hx3, xcat);
  k_fc1  <<<250,256, 0, stream>>>(xcat, fw1, y1raw);
  k_gelu1<<<32, 256, 0, stream>>>(y1raw, fb1, x1);
  k_fc2  <<<25, 256, 0, stream>>>(x1, fw2, fb2, x2);
  k_fc3  <<<1, 128, 0, stream>>>(x2, fw3, fb3, out);
}